// Round 2
// baseline (113.012 us; speedup 1.0000x reference)
//
#include <hip/hip_runtime.h>

// out[b,h,i,j] = x[b,h,i,j] * clamp(((ring(i,j)-127) + cv*256)/32 + 1, 0, 1)
// ring(i,j) = min(i, j, 255-i, 255-j); plane 256x256; fp32; memory-bound.
//
// Grid-stride = 2048 blk * 256 thr * 4 elem = 2,097,152 elems = exactly 32
// planes, so each thread's (row,col) within the plane is loop-invariant:
// compute the mask float4 ONCE, then the loop is load -> 4 muls -> store.

__global__ __launch_bounds__(256) void AdaptiveMask_kernel(
    const float4* __restrict__ x,
    const float* __restrict__ cvp,
    float4* __restrict__ out,
    int total4)
{
    const float cv256 = cvp[0] * 256.0f;

    const int idx    = blockIdx.x * blockDim.x + threadIdx.x;
    const int stride = gridDim.x * blockDim.x;   // 524288 float4 = 32 planes

    // Loop-invariant mask for this thread's (row, col-group).
    const int e  = idx << 2;           // element index of first component
    const int r  = (e >> 8) & 255;     // row within plane
    const int c  = e & 255;            // col of component 0
    const int rr = min(r, 255 - r);

    float4 m;
    {
        const int col  = c + 0;
        const int ring = min(rr, min(col, 255 - col));
        const float t  = (float)(ring - 127) + cv256;
        m.x = fminf(fmaxf(t * 0.03125f + 1.0f, 0.0f), 1.0f);
    }
    {
        const int col  = c + 1;
        const int ring = min(rr, min(col, 255 - col));
        const float t  = (float)(ring - 127) + cv256;
        m.y = fminf(fmaxf(t * 0.03125f + 1.0f, 0.0f), 1.0f);
    }
    {
        const int col  = c + 2;
        const int ring = min(rr, min(col, 255 - col));
        const float t  = (float)(ring - 127) + cv256;
        m.z = fminf(fmaxf(t * 0.03125f + 1.0f, 0.0f), 1.0f);
    }
    {
        const int col  = c + 3;
        const int ring = min(rr, min(col, 255 - col));
        const float t  = (float)(ring - 127) + cv256;
        m.w = fminf(fmaxf(t * 0.03125f + 1.0f, 0.0f), 1.0f);
    }

    #pragma unroll 2
    for (int i = idx; i < total4; i += stride) {
        float4 v = x[i];
        float4 o;
        o.x = v.x * m.x;
        o.y = v.y * m.y;
        o.z = v.z * m.z;
        o.w = v.w * m.w;
        out[i] = o;
    }
}

extern "C" void kernel_launch(void* const* d_in, const int* in_sizes, int n_in,
                              void* d_out, int out_size, void* d_ws, size_t ws_size,
                              hipStream_t stream) {
    const float4* x  = (const float4*)d_in[0];
    const float*  cv = (const float*)d_in[1];
    float4* out = (float4*)d_out;

    const int total4 = out_size / 4;   // 16,777,216 / 4 = 4,194,304

    const int block = 256;
    const int grid  = 2048;            // 32 waves/CU worth of threads; 8 iters each

    AdaptiveMask_kernel<<<grid, block, 0, stream>>>(x, cv, out, total4);
}